// Round 19
// baseline (34.691 us; speedup 1.0000x reference)
//
#include <hip/hip_runtime.h>
#include <hip/hip_bf16.h>

#define E 1024
#define F 12
#define BM 16   // rows per tile = one wave's MFMA M

typedef float f32x4_t __attribute__((ext_vector_type(4)));
typedef short bf16x8  __attribute__((ext_vector_type(8)));

// float -> bf16 bits (RNE)
__device__ __forceinline__ short f2bf(float f) {
    return (short)__builtin_bit_cast(unsigned short, __float2bfloat16(f));
}

// One wave per 16-row tile, full K=1024, ZERO barriers, zero cross-wave traffic.
// 1024 independent waves drift freely -> read/write streams overlap chip-wide.
__global__ __launch_bounds__(64, 2) void ffq_wave(
    const float* __restrict__ x,
    const float* __restrict__ W1,
    const float* __restrict__ b1,
    const float* __restrict__ theta,
    const float* __restrict__ W2,
    const float* __restrict__ b2,
    float* __restrict__ out, int nrows)
{
    const int lane = threadIdx.x & 63;
    const int g    = lane >> 4;    // k sub-group (A) / C row group
    const int n    = lane & 15;    // A row (m) on loads / C col (f)

    const int row0 = blockIdx.x * BM;
    if (row0 >= nrows) return;

    __shared__ __align__(16) float qsh[16][20];   // wave-private q tile

    const int nc = (n < F) ? n : (F - 1);         // clamp: C cols 12..15 unused
    const float b1n = b1[nc], thn = theta[nc];

    // ---------------- phase 1: h = x . W1^T, full K in one wave ----------------
    // A slot (g,j) <- x[row0+n][kb*32 + g*8 + j]; B slot (g,j) <- W1[nc][same k].
    // Same (g,j)->k map for A and B => contraction correct for any bijection.
    const int mrow = min(row0 + n, nrows - 1);
    const float* xrow = x  + (size_t)mrow * E + g * 8;
    const float* wrow = W1 + (size_t)nc   * E + g * 8;

    f32x4_t acc0 = {0.f, 0.f, 0.f, 0.f}, acc1 = {0.f, 0.f, 0.f, 0.f};
#pragma unroll
    for (int kb = 0; kb < 32; ++kb) {             // 32 MFMAs, 2 indep acc chains
        f32x4_t a0 = *reinterpret_cast<const f32x4_t*>(xrow + kb * 32);
        f32x4_t a1 = *reinterpret_cast<const f32x4_t*>(xrow + kb * 32 + 4);
        f32x4_t b0 = *reinterpret_cast<const f32x4_t*>(wrow + kb * 32);
        f32x4_t b1v= *reinterpret_cast<const f32x4_t*>(wrow + kb * 32 + 4);
        bf16x8 af, bfr;
#pragma unroll
        for (int j = 0; j < 4; ++j) {
            af[j]      = f2bf(a0[j]);
            af[j + 4]  = f2bf(a1[j]);
            bfr[j]     = f2bf(b0[j]);
            bfr[j + 4] = f2bf(b1v[j]);
        }
        if (kb & 1) acc1 = __builtin_amdgcn_mfma_f32_16x16x32_bf16(af, bfr, acc1, 0, 0, 0);
        else        acc0 = __builtin_amdgcn_mfma_f32_16x16x32_bf16(af, bfr, acc0, 0, 0, 0);
    }

    // ---- finisher: fully in-wave. C[m=g*4+j][col n] -> q -> LDS transpose ----
    {
        f32x4_t s = acc0 + acc1;
#pragma unroll
        for (int j = 0; j < 4; ++j)
            qsh[g * 4 + j][n] = __cosf(fmaxf(s[j] + b1n, 0.0f) + thn);
    }
    // qsh write -> read is same-wave program order (compiler inserts lgkmcnt);
    // NO barrier anywhere in this kernel.

    // ---------------- phase 2: out = q . W2^T + b2, 4 E-chunks ----------------
#pragma unroll
    for (int c = 0; c < 4; ++c) {
        const int e0 = c * 256 + lane * 4;        // this lane's 4 output cols

        float w2l[48];                            // W2[(e0+j)][f] = w2l[12j+f]
#pragma unroll
        for (int k2 = 0; k2 < 12; ++k2)
            *reinterpret_cast<f32x4_t*>(&w2l[4 * k2]) =
                *reinterpret_cast<const f32x4_t*>(W2 + (size_t)e0 * F + 4 * k2);
        const f32x4_t bias2 = *reinterpret_cast<const f32x4_t*>(b2 + e0);

#pragma unroll 4
        for (int m = 0; m < BM; ++m) {
            if (row0 + m < nrows) {
                float qf[F];
                *reinterpret_cast<f32x4_t*>(&qf[0]) = *reinterpret_cast<const f32x4_t*>(&qsh[m][0]);
                *reinterpret_cast<f32x4_t*>(&qf[4]) = *reinterpret_cast<const f32x4_t*>(&qsh[m][4]);
                *reinterpret_cast<f32x4_t*>(&qf[8]) = *reinterpret_cast<const f32x4_t*>(&qsh[m][8]);

                f32x4_t o;
#pragma unroll
                for (int j = 0; j < 4; ++j) {
                    float a = bias2[j];
#pragma unroll
                    for (int f = 0; f < F; ++f) a = fmaf(qf[f], w2l[12 * j + f], a);
                    o[j] = a;
                }
                __builtin_nontemporal_store(o,
                    reinterpret_cast<f32x4_t*>(out + (size_t)(row0 + m) * E + e0));
            }
        }
    }
}

extern "C" void kernel_launch(void* const* d_in, const int* in_sizes, int n_in,
                              void* d_out, int out_size, void* d_ws, size_t ws_size,
                              hipStream_t stream)
{
    const float* x     = (const float*)d_in[0];
    const float* W1    = (const float*)d_in[1];
    const float* b1    = (const float*)d_in[2];
    const float* theta = (const float*)d_in[3];
    const float* W2    = (const float*)d_in[4];
    const float* b2    = (const float*)d_in[5];
    float* out = (float*)d_out;

    const int nrows = in_sizes[0] / E;             // B*S = 16384
    const int grid  = (nrows + BM - 1) / BM;       // 1024 one-wave blocks

    ffq_wave<<<grid, 64, 0, stream>>>(x, W1, b1, theta, W2, b2, out, nrows);
}